// Round 4
// baseline (81.573 us; speedup 1.0000x reference)
//
#include <hip/hip_runtime.h>
#include <math.h>

// Problem constants: L=5, B=8, n=1024, d=64
#define LL 5
#define BB 8
#define NN 1024
#define DD 64
#define LB (LL * BB)      // 40 (l,b) pairs -> 40 blocks
#define ZC (2 * DD)       // Z = [X | Y], 128 columns
#define CHUNK 128         // K rows staged per LDS chunk
#define NCH (NN / CHUNK)  // 8 chunks

typedef short short8 __attribute__((ext_vector_type(8)));   // 8 bf16 = 4 VGPRs
typedef float floatx4 __attribute__((ext_vector_type(4)));  // MFMA C/D

__device__ __forceinline__ unsigned short f2bf(float f) {
    union { float f; unsigned u; } v; v.f = f;
    const unsigned u = v.u;
    return (unsigned short)((u + 0x7FFFu + ((u >> 16) & 1u)) >> 16);  // RNE
}
__device__ __forceinline__ float bf2f(unsigned short h) {
    union { unsigned u; float f; } v; v.u = ((unsigned)h) << 16; return v.f;
}

// LDS chunk layout: col-major (K-contiguous) bf16, XOR-octet swizzle.
// Element (c, k): short-index c*128 + ((k>>3) ^ (c&15))*8 + (k&7).
// Frag read (tile base t, k-block k0): one aligned 16B ds_read_b128/lane,
// bank-quad = ((k0>>3 + lane>>4) ^ (lane&15)) & 7 -> exactly 8 lanes per
// bank-quad = conflict-free floor.
__device__ __forceinline__ short8 read_frag(const short* Zt, int t, int lane, int k0) {
    const int c = t + (lane & 15);
    const int o = (k0 >> 3) + (lane >> 4);
    return *(const short8*)(Zt + c * 128 + ((o ^ (c & 15)) << 3));
}

// One block per (l,b). 512 threads = 8 waves. Wave w: quadrant qd=w&3
// (64x64 tile of the 128x128 gram), K-half hf=w>>2. Full gram, centering,
// Frobenius sums, and the CKA ratio all computed in-block. Output: R[lb].
__global__ __launch_bounds__(512) void gram_fused(const float* __restrict__ X,
                                                  const float* __restrict__ Y,
                                                  float* __restrict__ R) {
    __shared__ short Zt[2][CHUNK * ZC];   // 2 x 32 KB double-buffered bf16
    __shared__ float csum_sh[4][ZC];
    __shared__ float stot[ZC];
    __shared__ float red[4];

    const int lb = blockIdx.x;
    const int tid = threadIdx.x;
    const int c = tid & 127;              // Z column this thread stages
    const int qq = tid >> 7;              // 0..3: quarter of k-pairs per chunk

    const float* src = (c < DD) ? (X + (size_t)lb * NN * DD + c)
                                : (Y + (size_t)lb * NN * DD + (c - DD));

    const int lane = tid & 63, w = tid >> 6;
    const int qd = w & 3, hf = w >> 2;
    const int wr = (qd >> 1) << 6;        // quadrant row base
    const int wc_ = (qd & 1) << 6;        // quadrant col base

    floatx4 acc[4][4];
#pragma unroll
    for (int i = 0; i < 4; ++i)
#pragma unroll
        for (int j = 0; j < 4; ++j)
            acc[i][j] = (floatx4){0.f, 0.f, 0.f, 0.f};
    float csum = 0.0f;

    // ---- stage chunk 0 ----
    {
        short* Bn = Zt[0];
#pragma unroll
        for (int j = 0; j < 16; ++j) {
            const int kp = qq * 16 + j;                       // k-pair in chunk
            const float v0 = src[(size_t)(2 * kp) * DD];
            const float v1 = src[(size_t)(2 * kp + 1) * DD];
            const unsigned short b0 = f2bf(v0), b1 = f2bf(v1);
            csum += bf2f(b0) + bf2f(b1);
            const unsigned val = (unsigned)b0 | ((unsigned)b1 << 16);
            const int o = kp >> 2, dw = kp & 3;
            *(unsigned*)((char*)Bn + (c << 8) + (((o ^ (c & 15)) << 4) + (dw << 2))) = val;
        }
    }
    __syncthreads();

    // ---- main loop: MFMA on current buffer, stage next into the other ----
    for (int ch = 0; ch < NCH; ++ch) {
        const short* B = Zt[ch & 1];
        if (ch + 1 < NCH) {
            const int rbase = (ch + 1) * CHUNK;
            short* Bn = Zt[(ch + 1) & 1];
#pragma unroll
            for (int j = 0; j < 16; ++j) {
                const int kp = qq * 16 + j;
                const float v0 = src[(size_t)(rbase + 2 * kp) * DD];
                const float v1 = src[(size_t)(rbase + 2 * kp + 1) * DD];
                const unsigned short b0 = f2bf(v0), b1 = f2bf(v1);
                csum += bf2f(b0) + bf2f(b1);
                const unsigned val = (unsigned)b0 | ((unsigned)b1 << 16);
                const int o = kp >> 2, dw = kp & 3;
                *(unsigned*)((char*)Bn + (c << 8) + (((o ^ (c & 15)) << 4) + (dw << 2))) = val;
            }
        }
        // this wave's K-half of the chunk: k0 in {hf*64, hf*64+32}
#pragma unroll
        for (int s = 0; s < 2; ++s) {
            const int k0 = hf * 64 + s * 32;
            short8 af[4], bfr[4];
#pragma unroll
            for (int i = 0; i < 4; ++i) af[i] = read_frag(B, wr + i * 16, lane, k0);
#pragma unroll
            for (int j = 0; j < 4; ++j) bfr[j] = read_frag(B, wc_ + j * 16, lane, k0);
#pragma unroll
            for (int i = 0; i < 4; ++i)
#pragma unroll
                for (int j = 0; j < 4; ++j)
                    acc[i][j] = __builtin_amdgcn_mfma_f32_16x16x32_bf16(af[i], bfr[j], acc[i][j], 0, 0, 0);
        }
        __syncthreads();
    }

    // ---- epilogue ----
    csum_sh[qq][c] = csum;
    float* scr = (float*)Zt;   // reuse 64 KB staging LDS as merge scratch
    __syncthreads();

    const int g = lane >> 4, cl = lane & 15;
    // K-half 0 waves park their partial quadrant in scratch
    if (hf == 0) {
#pragma unroll
        for (int i = 0; i < 4; ++i)
#pragma unroll
            for (int j = 0; j < 4; ++j)
#pragma unroll
                for (int r = 0; r < 4; ++r)
                    scr[qd * 4096 + (i * 16 + g * 4 + r) * 64 + (j * 16 + cl)] = acc[i][j][r];
    }
    if (tid < ZC)
        stot[tid] = csum_sh[0][tid] + csum_sh[1][tid] + csum_sh[2][tid] + csum_sh[3][tid];
    __syncthreads();

    // K-half 1 waves merge, center (Gc = G - s s^T / n), square-accumulate.
    // Quadrants: 0 = Xc^T Xc (vxx), 1 = Xc^T Yc (hsic), 3 = Yc^T Yc (vyy);
    // quadrant 2 is the symmetric duplicate — skipped.
    if (hf == 1 && qd != 2) {
        const float inv_n = 1.0f / (float)NN;
        float sq = 0.0f;
#pragma unroll
        for (int i = 0; i < 4; ++i)
#pragma unroll
            for (int j = 0; j < 4; ++j) {
                const int col = wc_ + j * 16 + cl;
                const float sc = stot[col] * inv_n;
#pragma unroll
                for (int r = 0; r < 4; ++r) {
                    const int row = wr + i * 16 + g * 4 + r;
                    const float v = acc[i][j][r] + scr[qd * 4096 + (i * 16 + g * 4 + r) * 64 + (j * 16 + cl)];
                    const float cv = v - stot[row] * sc;
                    sq += cv * cv;
                }
            }
#pragma unroll
        for (int off = 32; off; off >>= 1) sq += __shfl_down(sq, off);
        if (lane == 0) red[qd] = sq;
    }
    __syncthreads();
    if (tid == 0) {
        const float vxx = red[0], hxy = red[1], vyy = red[3];
        R[lb] = fabsf(hxy / (sqrtf(vxx) * sqrtf(vyy)));
    }
}

// loss = mean_l( -log( mean_b(ratio) + eps ) )
__global__ void final_kernel(const float* __restrict__ R, float* __restrict__ out) {
    const int tid = threadIdx.x;   // one wave
    float v = (tid < LB) ? R[tid] : 0.0f;
    v += __shfl_xor(v, 1);
    v += __shfl_xor(v, 2);
    v += __shfl_xor(v, 4);
    float loss = 0.0f;
#pragma unroll
    for (int l = 0; l < LL; ++l) {
        const float sl = __shfl(v, l * BB);
        loss += -logf(sl * (1.0f / (float)BB) + 1e-8f);
    }
    if (tid == 0) out[0] = loss * (1.0f / (float)LL);
}

extern "C" void kernel_launch(void* const* d_in, const int* in_sizes, int n_in,
                              void* d_out, int out_size, void* d_ws, size_t ws_size,
                              hipStream_t stream) {
    const float* teacher = (const float*)d_in[0];
    const float* student = (const float*)d_in[1];
    float* R = (float*)d_ws;   // 40 floats, written unconditionally — no memset needed

    gram_fused<<<LB, 512, 0, stream>>>(teacher, student, R);
    final_kernel<<<1, 64, 0, stream>>>(R, (float*)d_out);
}